// Round 8
// baseline (3674.052 us; speedup 1.0000x reference)
//
#include <hip/hip_runtime.h>

#define B_SZ 16384

// ---------- one-time weight transpose: dst[C][R] = src[R][C]^T ----------
__global__ __launch_bounds__(256) void k_transpose(const float* __restrict__ src,
                                                   float* __restrict__ dst,
                                                   int R, int C) {
    __shared__ float tile[32][33];
    int bx = blockIdx.x * 32, by = blockIdx.y * 32;
    int tx = threadIdx.x & 31, ty = threadIdx.x >> 5;
#pragma unroll
    for (int r = ty; r < 32; r += 8) {
        int gr = by + r, gc = bx + tx;
        if (gr < R && gc < C) tile[r][tx] = src[gr * C + gc];
    }
    __syncthreads();
#pragma unroll
    for (int r = ty; r < 32; r += 8) {
        int gr = bx + r, gc = by + tx;
        if (gr < C && gc < R) dst[gr * R + gc] = tile[tx][r];
    }
}

// Spike LDS layout: sp[ip][g][e] = spike of neuron i=2*ip+e, sample g.
// One b128 read at (ip, g0=r*2) returns rows {2ip,2ip+1} x samples {g0,g0+1},
// and the wave's 8 distinct addresses span 128B = all 32 banks.

// 256->256 matmul: thread owns (8 j, 2 g). Ascending-i f32 FMA chain per (j,g).
__device__ __forceinline__ void mm256_8x2(const float* __restrict__ WT,
                                          const float (*sp)[16][2],
                                          const int* flagrow, int q, int r,
                                          float* acc) {
#pragma unroll
    for (int k = 0; k < 16; ++k) acc[k] = 0.f;
    int4 f = *(const int4*)flagrow;
    if ((f.x | f.y | f.z | f.w) == 0) return;          // silent input => acc=+0 exactly
#pragma unroll 2
    for (int ip = 0; ip < 128; ++ip) {
        float4 s4 = *(const float4*)&sp[ip][r * 2][0]; // {s[2ip][g0],s[2ip+1][g0],s[2ip][g0+1],s[2ip+1][g0+1]}
        const float* w0 = WT + (2 * ip) * 256 + q * 8;
        float4 wa0 = *(const float4*)(w0);
        float4 wa1 = *(const float4*)(w0 + 4);
        float4 wb0 = *(const float4*)(w0 + 256);
        float4 wb1 = *(const float4*)(w0 + 260);
        // acc[jj*2+gg]; per chain: row 2ip then row 2ip+1 (ascending i)
        acc[0]  = fmaf(s4.x, wa0.x, acc[0]);  acc[0]  = fmaf(s4.y, wb0.x, acc[0]);
        acc[1]  = fmaf(s4.z, wa0.x, acc[1]);  acc[1]  = fmaf(s4.w, wb0.x, acc[1]);
        acc[2]  = fmaf(s4.x, wa0.y, acc[2]);  acc[2]  = fmaf(s4.y, wb0.y, acc[2]);
        acc[3]  = fmaf(s4.z, wa0.y, acc[3]);  acc[3]  = fmaf(s4.w, wb0.y, acc[3]);
        acc[4]  = fmaf(s4.x, wa0.z, acc[4]);  acc[4]  = fmaf(s4.y, wb0.z, acc[4]);
        acc[5]  = fmaf(s4.z, wa0.z, acc[5]);  acc[5]  = fmaf(s4.w, wb0.z, acc[5]);
        acc[6]  = fmaf(s4.x, wa0.w, acc[6]);  acc[6]  = fmaf(s4.y, wb0.w, acc[6]);
        acc[7]  = fmaf(s4.z, wa0.w, acc[7]);  acc[7]  = fmaf(s4.w, wb0.w, acc[7]);
        acc[8]  = fmaf(s4.x, wa1.x, acc[8]);  acc[8]  = fmaf(s4.y, wb1.x, acc[8]);
        acc[9]  = fmaf(s4.z, wa1.x, acc[9]);  acc[9]  = fmaf(s4.w, wb1.x, acc[9]);
        acc[10] = fmaf(s4.x, wa1.y, acc[10]); acc[10] = fmaf(s4.y, wb1.y, acc[10]);
        acc[11] = fmaf(s4.z, wa1.y, acc[11]); acc[11] = fmaf(s4.w, wb1.y, acc[11]);
        acc[12] = fmaf(s4.x, wa1.z, acc[12]); acc[12] = fmaf(s4.y, wb1.z, acc[12]);
        acc[13] = fmaf(s4.z, wa1.z, acc[13]); acc[13] = fmaf(s4.w, wb1.z, acc[13]);
        acc[14] = fmaf(s4.x, wa1.w, acc[14]); acc[14] = fmaf(s4.y, wb1.w, acc[14]);
        acc[15] = fmaf(s4.z, wa1.w, acc[15]); acc[15] = fmaf(s4.w, wb1.w, acc[15]);
    }
}

// 256->128 matmul: thread owns (4 j, 2 g)
__device__ __forceinline__ void mm128_4x2(const float* __restrict__ WT5,
                                          const float (*sp)[16][2],
                                          const int* flagrow, int q, int r,
                                          float* acc) {
#pragma unroll
    for (int k = 0; k < 8; ++k) acc[k] = 0.f;
    int4 f = *(const int4*)flagrow;
    if ((f.x | f.y | f.z | f.w) == 0) return;
#pragma unroll 2
    for (int ip = 0; ip < 128; ++ip) {
        float4 s4 = *(const float4*)&sp[ip][r * 2][0];
        const float* w0 = WT5 + (2 * ip) * 128 + q * 4;
        float4 wa = *(const float4*)(w0);
        float4 wb = *(const float4*)(w0 + 128);
        acc[0] = fmaf(s4.x, wa.x, acc[0]); acc[0] = fmaf(s4.y, wb.x, acc[0]);
        acc[1] = fmaf(s4.z, wa.x, acc[1]); acc[1] = fmaf(s4.w, wb.x, acc[1]);
        acc[2] = fmaf(s4.x, wa.y, acc[2]); acc[2] = fmaf(s4.y, wb.y, acc[2]);
        acc[3] = fmaf(s4.z, wa.y, acc[3]); acc[3] = fmaf(s4.w, wb.y, acc[3]);
        acc[4] = fmaf(s4.x, wa.z, acc[4]); acc[4] = fmaf(s4.y, wb.z, acc[4]);
        acc[5] = fmaf(s4.z, wa.z, acc[5]); acc[5] = fmaf(s4.w, wb.z, acc[5]);
        acc[6] = fmaf(s4.x, wa.w, acc[6]); acc[6] = fmaf(s4.y, wb.w, acc[6]);
        acc[7] = fmaf(s4.z, wa.w, acc[7]); acc[7] = fmaf(s4.w, wb.w, acc[7]);
    }
}

// LIF + spike write, (8j,2g) ownership. Writes j-pairs as float2 into sp[jp][g][*].
__device__ __forceinline__ int lif8x2(float* m, const float* acc, const float* b8,
                                      float beta, float (*sp)[16][2], int j0, int g0) {
    int any = 0;
#pragma unroll
    for (int k2 = 0; k2 < 4; ++k2) {
        float2 spA, spB;
#pragma unroll
        for (int e = 0; e < 2; ++e) {
            int jj = 2 * k2 + e;
#pragma unroll
            for (int gg = 0; gg < 2; ++gg) {
                int k = jj * 2 + gg;
                float cur = acc[k] + b8[jj];
                float mp  = m[k];
                float mn  = fmaf(beta, mp, cur) - (mp > 1.f ? 1.f : 0.f);
                m[k] = mn;
                int s1 = (mn > 1.f);
                any |= s1;
                float sv = s1 ? 1.f : 0.f;
                if (gg == 0) ((float*)&spA)[e] = sv; else ((float*)&spB)[e] = sv;
            }
        }
        *(float2*)&sp[(j0 >> 1) + k2][g0][0]     = spA;
        *(float2*)&sp[(j0 >> 1) + k2][g0 + 1][0] = spB;
    }
    return any;
}

// LIF + spike write, (4j,2g) ownership (layer 5)
__device__ __forceinline__ int lif4x2(float* m, const float* acc, const float* b4v,
                                      float (*sp)[16][2], int j05, int g0) {
    int any = 0;
#pragma unroll
    for (int k2 = 0; k2 < 2; ++k2) {
        float2 spA, spB;
#pragma unroll
        for (int e = 0; e < 2; ++e) {
            int jj = 2 * k2 + e;
#pragma unroll
            for (int gg = 0; gg < 2; ++gg) {
                int k = jj * 2 + gg;
                float cur = acc[k] + b4v[jj];
                float mp  = m[k];
                float mn  = fmaf(0.82f, mp, cur) - (mp > 1.f ? 1.f : 0.f);
                m[k] = mn;
                int s1 = (mn > 1.f);
                any |= s1;
                float sv = s1 ? 1.f : 0.f;
                if (gg == 0) ((float*)&spA)[e] = sv; else ((float*)&spB)[e] = sv;
            }
        }
        *(float2*)&sp[(j05 >> 1) + k2][g0][0]     = spA;
        *(float2*)&sp[(j05 >> 1) + k2][g0 + 1][0] = spB;
    }
    return any;
}

__global__ __launch_bounds__(256, 3) void k_snn(
    const float* __restrict__ x,   const float* __restrict__ W1, const float* __restrict__ b1,
    const float* __restrict__ Wt2, const float* __restrict__ b2,
    const float* __restrict__ Wt3, const float* __restrict__ b3,
    const float* __restrict__ Wt4, const float* __restrict__ b4,
    const float* __restrict__ Wt5, const float* __restrict__ b5,
    const float* __restrict__ W6,  const float* __restrict__ b6,
    float* __restrict__ out)
{
    __shared__ __align__(16) float sppA[128][16][2];   // ping
    __shared__ __align__(16) float sppB[128][16][2];   // pong
    __shared__ float w6l[3][128];
    __shared__ float xl[16][8];
    __shared__ __align__(16) int flags[5][4];

    const int t    = threadIdx.x;
    const int s0   = blockIdx.x * 16;
    const int q    = t >> 3;          // 0..31
    const int r    = t & 7;           // 0..7
    const int j0   = q * 8;           // L1-4 output block
    const int j05  = q * 4;           // L5 output block
    const int g0   = r * 2;           // sample pair
    const int lane = t & 63, wvid = t >> 6;

    for (int k = t; k < 384; k += 256) ((float*)w6l)[k] = W6[k];
    if (t < 128) { int g = t >> 3, c = t & 7; xl[g][c] = (c < 6) ? x[(s0 + g) * 6 + c] : 0.f; }
    __syncthreads();

    float b2r[8], b3r[8], b4r[8], b5r[4];
    *(float4*)&b2r[0] = *(const float4*)&b2[j0]; *(float4*)&b2r[4] = *(const float4*)&b2[j0 + 4];
    *(float4*)&b3r[0] = *(const float4*)&b3[j0]; *(float4*)&b3r[4] = *(const float4*)&b3[j0 + 4];
    *(float4*)&b4r[0] = *(const float4*)&b4[j0]; *(float4*)&b4r[4] = *(const float4*)&b4[j0 + 4];
    *(float4*)&b5r[0] = *(const float4*)&b5[j05];
    const int og = t / 3, ok = t - og * 3;
    const float b6v = (t < 48) ? b6[ok] : 0.f;

    // layer-1 input current (constant over steps), bias folded in; ascending-k chain
    float cur1[16];
#pragma unroll
    for (int jj = 0; jj < 8; ++jj) {
        float w1r[6];
#pragma unroll
        for (int k = 0; k < 6; ++k) w1r[k] = W1[(j0 + jj) * 6 + k];
        float bb = b1[j0 + jj];
#pragma unroll
        for (int gg = 0; gg < 2; ++gg) {
            float s = 0.f;
#pragma unroll
            for (int k = 0; k < 6; ++k) s = fmaf(xl[g0 + gg][k], w1r[k], s);
            cur1[jj * 2 + gg] = s + bb;
        }
    }

    float m1[16], m2[16], m3[16], m4[16], m5[8], acc[16];
#pragma unroll
    for (int k = 0; k < 16; ++k) { m1[k] = 0.f; m2[k] = 0.f; m3[k] = 0.f; m4[k] = 0.f; }
#pragma unroll
    for (int k = 0; k < 8; ++k) m5[k] = 0.f;
    float accout = 0.f;
    const float zb8[8] = {0.f,0.f,0.f,0.f,0.f,0.f,0.f,0.f};

#define SETFLAG(L) { unsigned long long bl = __ballot(any); if (lane == 0) flags[L][wvid] = (bl != 0ULL) ? 1 : 0; }

    // One timestep; SX/SY ping-pong. 5 barriers per step. Cross-step hazards
    // covered by the post-L1 barrier of the following step (see analysis).
#define STEP(SX, SY)                                                            \
    { int any = lif8x2(m1, cur1, zb8, 0.9f, SX, j0, g0); SETFLAG(0); }          \
    __syncthreads();                                                            \
    mm256_8x2(Wt2, SX, &flags[0][0], q, r, acc);                                \
    { int any = lif8x2(m2, acc, b2r, 0.88f, SY, j0, g0); SETFLAG(1); }          \
    __syncthreads();                                                            \
    mm256_8x2(Wt3, SY, &flags[1][0], q, r, acc);                                \
    { int any = lif8x2(m3, acc, b3r, 0.86f, SX, j0, g0); SETFLAG(2); }          \
    __syncthreads();                                                            \
    mm256_8x2(Wt4, SX, &flags[2][0], q, r, acc);                                \
    { int any = lif8x2(m4, acc, b4r, 0.84f, SY, j0, g0); SETFLAG(3); }          \
    __syncthreads();                                                            \
    mm128_4x2(Wt5, SY, &flags[3][0], q, r, acc);                                \
    { int any = lif4x2(m5, acc, b5r, SX, j05, g0); SETFLAG(4); }                \
    __syncthreads();                                                            \
    { int4 f = *(const int4*)&flags[4][0];                                      \
      if (t < 48) {                                                             \
          float s = 0.f;                                                        \
          if (f.x | f.y | f.z | f.w) {                                          \
              _Pragma("unroll 4")                                               \
              for (int ip = 0; ip < 64; ++ip) {                                 \
                  float2 sv = *(const float2*)&SX[ip][og][0];                   \
                  s = fmaf(sv.x, w6l[ok][2 * ip], s);                           \
                  s = fmaf(sv.y, w6l[ok][2 * ip + 1], s);                       \
              }                                                                 \
          }                                                                     \
          accout += s + b6v;                                                    \
      } }

#pragma unroll 1
    for (int s2 = 0; s2 < 7; ++s2) {
        STEP(sppA, sppB)
        STEP(sppB, sppA)
    }
    STEP(sppA, sppB)
#undef STEP
#undef SETFLAG

    if (t < 48) out[(s0 + og) * 3 + ok] = accout / 15.0f;
}

extern "C" void kernel_launch(void* const* d_in, const int* in_sizes, int n_in,
                              void* d_out, int out_size, void* d_ws, size_t ws_size,
                              hipStream_t stream) {
    const float* x  = (const float*)d_in[0];
    const float* W1 = (const float*)d_in[1];
    const float* b1 = (const float*)d_in[2];
    const float* W2 = (const float*)d_in[3];
    const float* b2 = (const float*)d_in[4];
    const float* W3 = (const float*)d_in[5];
    const float* b3 = (const float*)d_in[6];
    const float* W4 = (const float*)d_in[7];
    const float* b4 = (const float*)d_in[8];
    const float* W5 = (const float*)d_in[9];
    const float* b5 = (const float*)d_in[10];
    const float* W6 = (const float*)d_in[11];
    const float* b6 = (const float*)d_in[12];
    float* out = (float*)d_out;

    float* ws  = (float*)d_ws;
    float* Wt2 = ws;                 // [256][256]
    float* Wt3 = Wt2 + 65536;
    float* Wt4 = Wt3 + 65536;
    float* Wt5 = Wt4 + 65536;        // [256][128]
    size_t need = (size_t)(65536 * 3 + 32768) * sizeof(float);
    if (ws_size < need) return;

    k_transpose<<<dim3(8, 8), 256, 0, stream>>>(W2, Wt2, 256, 256);
    k_transpose<<<dim3(8, 8), 256, 0, stream>>>(W3, Wt3, 256, 256);
    k_transpose<<<dim3(8, 8), 256, 0, stream>>>(W4, Wt4, 256, 256);
    k_transpose<<<dim3(8, 4), 256, 0, stream>>>(W5, Wt5, 128, 256);
    k_snn<<<B_SZ / 16, 256, 0, stream>>>(x, W1, b1, Wt2, b2, Wt3, b3,
                                         Wt4, b4, Wt5, b5, W6, b6, out);
}

// Round 9
// 2406.926 us; speedup vs baseline: 1.5264x; 1.5264x over previous
//
#include <hip/hip_runtime.h>

#define B_SZ 16384

// ---------- one-time weight transpose: dst[C][R] = src[R][C]^T ----------
__global__ __launch_bounds__(256) void k_transpose(const float* __restrict__ src,
                                                   float* __restrict__ dst,
                                                   int R, int C) {
    __shared__ float tile[32][33];
    int bx = blockIdx.x * 32, by = blockIdx.y * 32;
    int tx = threadIdx.x & 31, ty = threadIdx.x >> 5;
#pragma unroll
    for (int r = ty; r < 32; r += 8) {
        int gr = by + r, gc = bx + tx;
        if (gr < R && gc < C) tile[r][tx] = src[gr * C + gc];
    }
    __syncthreads();
#pragma unroll
    for (int r = ty; r < 32; r += 8) {
        int gr = bx + r, gc = by + tx;
        if (gr < C && gc < R) dst[gr * R + gc] = tile[tx][r];
    }
}

// Spike LDS layout: sp[ip][g][e] = spike of neuron i=2*ip+e, sample g.
// One b128 read at (ip, g0=r*2) returns rows {2ip,2ip+1} x samples {g0,g0+1};
// the wave's 8 distinct addresses span 128B = all 32 banks (conflict-light, r8-verified).

// 256->256 matmul: thread owns (8 j, 2 g). Ascending-i f32 FMA chain per (j,g).
// Weight loads split in two 4-wide halves to cap live registers (r8 spill fix).
__device__ __forceinline__ void mm256_8x2(const float* __restrict__ WT,
                                          const float (*sp)[16][2],
                                          const int* flagrow, int q, int r,
                                          float* acc) {
#pragma unroll
    for (int k = 0; k < 16; ++k) acc[k] = 0.f;
    int4 f = *(const int4*)flagrow;
    if ((f.x | f.y | f.z | f.w) == 0) return;          // silent input => acc=+0 exactly
#pragma unroll 2
    for (int ip = 0; ip < 128; ++ip) {
        float4 s4 = *(const float4*)&sp[ip][r * 2][0]; // {s[2ip][g0],s[2ip+1][g0],s[2ip][g0+1],s[2ip+1][g0+1]}
        const float* w0 = WT + (2 * ip) * 256 + q * 8;
        {   // j 0..3
            float4 wa = *(const float4*)(w0);
            float4 wb = *(const float4*)(w0 + 256);
            acc[0] = fmaf(s4.x, wa.x, acc[0]); acc[0] = fmaf(s4.y, wb.x, acc[0]);
            acc[1] = fmaf(s4.z, wa.x, acc[1]); acc[1] = fmaf(s4.w, wb.x, acc[1]);
            acc[2] = fmaf(s4.x, wa.y, acc[2]); acc[2] = fmaf(s4.y, wb.y, acc[2]);
            acc[3] = fmaf(s4.z, wa.y, acc[3]); acc[3] = fmaf(s4.w, wb.y, acc[3]);
            acc[4] = fmaf(s4.x, wa.z, acc[4]); acc[4] = fmaf(s4.y, wb.z, acc[4]);
            acc[5] = fmaf(s4.z, wa.z, acc[5]); acc[5] = fmaf(s4.w, wb.z, acc[5]);
            acc[6] = fmaf(s4.x, wa.w, acc[6]); acc[6] = fmaf(s4.y, wb.w, acc[6]);
            acc[7] = fmaf(s4.z, wa.w, acc[7]); acc[7] = fmaf(s4.w, wb.w, acc[7]);
        }
        {   // j 4..7
            float4 wa = *(const float4*)(w0 + 4);
            float4 wb = *(const float4*)(w0 + 260);
            acc[8]  = fmaf(s4.x, wa.x, acc[8]);  acc[8]  = fmaf(s4.y, wb.x, acc[8]);
            acc[9]  = fmaf(s4.z, wa.x, acc[9]);  acc[9]  = fmaf(s4.w, wb.x, acc[9]);
            acc[10] = fmaf(s4.x, wa.y, acc[10]); acc[10] = fmaf(s4.y, wb.y, acc[10]);
            acc[11] = fmaf(s4.z, wa.y, acc[11]); acc[11] = fmaf(s4.w, wb.y, acc[11]);
            acc[12] = fmaf(s4.x, wa.z, acc[12]); acc[12] = fmaf(s4.y, wb.z, acc[12]);
            acc[13] = fmaf(s4.z, wa.z, acc[13]); acc[13] = fmaf(s4.w, wb.z, acc[13]);
            acc[14] = fmaf(s4.x, wa.w, acc[14]); acc[14] = fmaf(s4.y, wb.w, acc[14]);
            acc[15] = fmaf(s4.z, wa.w, acc[15]); acc[15] = fmaf(s4.w, wb.w, acc[15]);
        }
    }
}

// 256->128 matmul: thread owns (4 j, 2 g)
__device__ __forceinline__ void mm128_4x2(const float* __restrict__ WT5,
                                          const float (*sp)[16][2],
                                          const int* flagrow, int q, int r,
                                          float* acc) {
#pragma unroll
    for (int k = 0; k < 8; ++k) acc[k] = 0.f;
    int4 f = *(const int4*)flagrow;
    if ((f.x | f.y | f.z | f.w) == 0) return;
#pragma unroll 2
    for (int ip = 0; ip < 128; ++ip) {
        float4 s4 = *(const float4*)&sp[ip][r * 2][0];
        const float* w0 = WT5 + (2 * ip) * 128 + q * 4;
        float4 wa = *(const float4*)(w0);
        float4 wb = *(const float4*)(w0 + 128);
        acc[0] = fmaf(s4.x, wa.x, acc[0]); acc[0] = fmaf(s4.y, wb.x, acc[0]);
        acc[1] = fmaf(s4.z, wa.x, acc[1]); acc[1] = fmaf(s4.w, wb.x, acc[1]);
        acc[2] = fmaf(s4.x, wa.y, acc[2]); acc[2] = fmaf(s4.y, wb.y, acc[2]);
        acc[3] = fmaf(s4.z, wa.y, acc[3]); acc[3] = fmaf(s4.w, wb.y, acc[3]);
        acc[4] = fmaf(s4.x, wa.z, acc[4]); acc[4] = fmaf(s4.y, wb.z, acc[4]);
        acc[5] = fmaf(s4.z, wa.z, acc[5]); acc[5] = fmaf(s4.w, wb.z, acc[5]);
        acc[6] = fmaf(s4.x, wa.w, acc[6]); acc[6] = fmaf(s4.y, wb.w, acc[6]);
        acc[7] = fmaf(s4.z, wa.w, acc[7]); acc[7] = fmaf(s4.w, wb.w, acc[7]);
    }
}

// LIF + spike write, (8j,2g) ownership; bias via pointer (LDS or const array).
__device__ __forceinline__ int lif8x2(float* m, const float* acc, const float* b8,
                                      float beta, float (*sp)[16][2], int j0, int g0) {
    int any = 0;
#pragma unroll
    for (int k2 = 0; k2 < 4; ++k2) {
        float2 spA, spB;
#pragma unroll
        for (int e = 0; e < 2; ++e) {
            int jj = 2 * k2 + e;
            float bb = b8[jj];
#pragma unroll
            for (int gg = 0; gg < 2; ++gg) {
                int k = jj * 2 + gg;
                float cur = acc[k] + bb;
                float mp  = m[k];
                float mn  = fmaf(beta, mp, cur) - (mp > 1.f ? 1.f : 0.f);
                m[k] = mn;
                int s1 = (mn > 1.f);
                any |= s1;
                float sv = s1 ? 1.f : 0.f;
                if (gg == 0) ((float*)&spA)[e] = sv; else ((float*)&spB)[e] = sv;
            }
        }
        *(float2*)&sp[(j0 >> 1) + k2][g0][0]     = spA;
        *(float2*)&sp[(j0 >> 1) + k2][g0 + 1][0] = spB;
    }
    return any;
}

// LIF + spike write, (4j,2g) ownership (layer 5)
__device__ __forceinline__ int lif4x2(float* m, const float* acc, const float* b4v,
                                      float (*sp)[16][2], int j05, int g0) {
    int any = 0;
#pragma unroll
    for (int k2 = 0; k2 < 2; ++k2) {
        float2 spA, spB;
#pragma unroll
        for (int e = 0; e < 2; ++e) {
            int jj = 2 * k2 + e;
            float bb = b4v[jj];
#pragma unroll
            for (int gg = 0; gg < 2; ++gg) {
                int k = jj * 2 + gg;
                float cur = acc[k] + bb;
                float mp  = m[k];
                float mn  = fmaf(0.82f, mp, cur) - (mp > 1.f ? 1.f : 0.f);
                m[k] = mn;
                int s1 = (mn > 1.f);
                any |= s1;
                float sv = s1 ? 1.f : 0.f;
                if (gg == 0) ((float*)&spA)[e] = sv; else ((float*)&spB)[e] = sv;
            }
        }
        *(float2*)&sp[(j05 >> 1) + k2][g0][0]     = spA;
        *(float2*)&sp[(j05 >> 1) + k2][g0 + 1][0] = spB;
    }
    return any;
}

__global__ __launch_bounds__(256, 2) void k_snn(
    const float* __restrict__ x,   const float* __restrict__ W1, const float* __restrict__ b1,
    const float* __restrict__ Wt2, const float* __restrict__ b2,
    const float* __restrict__ Wt3, const float* __restrict__ b3,
    const float* __restrict__ Wt4, const float* __restrict__ b4,
    const float* __restrict__ Wt5, const float* __restrict__ b5,
    const float* __restrict__ W6,  const float* __restrict__ b6,
    float* __restrict__ out)
{
    __shared__ __align__(16) float sppA[128][16][2];   // ping
    __shared__ __align__(16) float sppB[128][16][2];   // pong
    __shared__ float w6l[3][128];
    __shared__ float xl[16][8];
    __shared__ float b2l[256], b3l[256], b4l[256], b5l[128];   // biases in LDS (saves 28 VGPR)
    __shared__ __align__(16) int flags[5][4];

    const int t    = threadIdx.x;
    const int s0   = blockIdx.x * 16;
    const int q    = t >> 3;          // 0..31
    const int r    = t & 7;           // 0..7
    const int j0   = q * 8;           // L1-4 output block
    const int j05  = q * 4;           // L5 output block
    const int g0   = r * 2;           // sample pair
    const int lane = t & 63, wvid = t >> 6;

    for (int k = t; k < 384; k += 256) ((float*)w6l)[k] = W6[k];
    b2l[t] = b2[t]; b3l[t] = b3[t]; b4l[t] = b4[t];
    if (t < 128) b5l[t] = b5[t];
    if (t < 128) { int g = t >> 3, c = t & 7; xl[g][c] = (c < 6) ? x[(s0 + g) * 6 + c] : 0.f; }
    __syncthreads();

    const int og = t / 3, ok = t - og * 3;
    const float b6v = (t < 48) ? b6[ok] : 0.f;

    // layer-1 input current (constant over steps), bias folded in; ascending-k chain
    float cur1[16];
#pragma unroll
    for (int jj = 0; jj < 8; ++jj) {
        float w1r[6];
#pragma unroll
        for (int k = 0; k < 6; ++k) w1r[k] = W1[(j0 + jj) * 6 + k];
        float bb = b1[j0 + jj];
#pragma unroll
        for (int gg = 0; gg < 2; ++gg) {
            float s = 0.f;
#pragma unroll
            for (int k = 0; k < 6; ++k) s = fmaf(xl[g0 + gg][k], w1r[k], s);
            cur1[jj * 2 + gg] = s + bb;
        }
    }

    float m1[16], m2[16], m3[16], m4[16], m5[8], acc[16];
#pragma unroll
    for (int k = 0; k < 16; ++k) { m1[k] = 0.f; m2[k] = 0.f; m3[k] = 0.f; m4[k] = 0.f; }
#pragma unroll
    for (int k = 0; k < 8; ++k) m5[k] = 0.f;
    float accout = 0.f;
    const float zb8[8] = {0.f,0.f,0.f,0.f,0.f,0.f,0.f,0.f};   // const: folds to inline 0

#define SETFLAG(L) { unsigned long long bl = __ballot(any); if (lane == 0) flags[L][wvid] = (bl != 0ULL) ? 1 : 0; }

    // One timestep; SX/SY ping-pong. 5 barriers per step.
#define STEP(SX, SY)                                                            \
    { int any = lif8x2(m1, cur1, zb8, 0.9f, SX, j0, g0); SETFLAG(0); }          \
    __syncthreads();                                                            \
    mm256_8x2(Wt2, SX, &flags[0][0], q, r, acc);                                \
    { int any = lif8x2(m2, acc, &b2l[j0], 0.88f, SY, j0, g0); SETFLAG(1); }     \
    __syncthreads();                                                            \
    mm256_8x2(Wt3, SY, &flags[1][0], q, r, acc);                                \
    { int any = lif8x2(m3, acc, &b3l[j0], 0.86f, SX, j0, g0); SETFLAG(2); }     \
    __syncthreads();                                                            \
    mm256_8x2(Wt4, SX, &flags[2][0], q, r, acc);                                \
    { int any = lif8x2(m4, acc, &b4l[j0], 0.84f, SY, j0, g0); SETFLAG(3); }     \
    __syncthreads();                                                            \
    mm128_4x2(Wt5, SY, &flags[3][0], q, r, acc);                                \
    { int any = lif4x2(m5, acc, &b5l[j05], SX, j05, g0); SETFLAG(4); }          \
    __syncthreads();                                                            \
    { int4 f = *(const int4*)&flags[4][0];                                      \
      if (t < 48) {                                                             \
          float s = 0.f;                                                        \
          if (f.x | f.y | f.z | f.w) {                                          \
              _Pragma("unroll 4")                                               \
              for (int ip = 0; ip < 64; ++ip) {                                 \
                  float2 sv = *(const float2*)&SX[ip][og][0];                   \
                  s = fmaf(sv.x, w6l[ok][2 * ip], s);                           \
                  s = fmaf(sv.y, w6l[ok][2 * ip + 1], s);                       \
              }                                                                 \
          }                                                                     \
          accout += s + b6v;                                                    \
      } }

#pragma unroll 1
    for (int s2 = 0; s2 < 7; ++s2) {
        STEP(sppA, sppB)
        STEP(sppB, sppA)
    }
    STEP(sppA, sppB)
#undef STEP
#undef SETFLAG

    if (t < 48) out[(s0 + og) * 3 + ok] = accout / 15.0f;
}

extern "C" void kernel_launch(void* const* d_in, const int* in_sizes, int n_in,
                              void* d_out, int out_size, void* d_ws, size_t ws_size,
                              hipStream_t stream) {
    const float* x  = (const float*)d_in[0];
    const float* W1 = (const float*)d_in[1];
    const float* b1 = (const float*)d_in[2];
    const float* W2 = (const float*)d_in[3];
    const float* b2 = (const float*)d_in[4];
    const float* W3 = (const float*)d_in[5];
    const float* b3 = (const float*)d_in[6];
    const float* W4 = (const float*)d_in[7];
    const float* b4 = (const float*)d_in[8];
    const float* W5 = (const float*)d_in[9];
    const float* b5 = (const float*)d_in[10];
    const float* W6 = (const float*)d_in[11];
    const float* b6 = (const float*)d_in[12];
    float* out = (float*)d_out;

    float* ws  = (float*)d_ws;
    float* Wt2 = ws;                 // [256][256]
    float* Wt3 = Wt2 + 65536;
    float* Wt4 = Wt3 + 65536;
    float* Wt5 = Wt4 + 65536;        // [256][128]
    size_t need = (size_t)(65536 * 3 + 32768) * sizeof(float);
    if (ws_size < need) return;

    k_transpose<<<dim3(8, 8), 256, 0, stream>>>(W2, Wt2, 256, 256);
    k_transpose<<<dim3(8, 8), 256, 0, stream>>>(W3, Wt3, 256, 256);
    k_transpose<<<dim3(8, 8), 256, 0, stream>>>(W4, Wt4, 256, 256);
    k_transpose<<<dim3(8, 4), 256, 0, stream>>>(W5, Wt5, 128, 256);
    k_snn<<<B_SZ / 16, 256, 0, stream>>>(x, W1, b1, Wt2, b2, Wt3, b3,
                                         Wt4, b4, Wt5, b5, W6, b6, out);
}